// Round 3
// baseline (1571.747 us; speedup 1.0000x reference)
//
#include <hip/hip_runtime.h>

// SpatialAttentionLSTMDecoder on MI355X (gfx950). B=128,T=32,V=10000,F=H=768,R=49.
// R3: 3 kernels per step: g1 GEMM (h@[Wh;Whh_int].T) -> fused attention
// (scores+softmax+ctx) -> g2 GEMM with fused LSTM epilogue (interleaved gates).

typedef _Float16 f16x8 __attribute__((ext_vector_type(8)));
typedef _Float16 f16x4 __attribute__((ext_vector_type(4)));
typedef float f32x4 __attribute__((ext_vector_type(4)));

#define NB 128
#define NT 32
#define NV 10000
#define NH 768
#define NR 49
#define OUT_ELEMS 40960000  // B*T*V

__device__ __forceinline__ float fast_tanh(float x) {
  x = fminf(9.f, fmaxf(-9.f, x));
  float e = __expf(2.f * x);
  return (e - 1.f) / (e + 1.f);
}
__device__ __forceinline__ float sigm(float x) { return 1.f / (1.f + __expf(-x)); }

__device__ __forceinline__ void gld16(const void* g, void* l) {
  __builtin_amdgcn_global_load_lds((const __attribute__((address_space(1))) void*)g,
                                   (__attribute__((address_space(3))) void*)l, 16, 0, 0);
}

// ---------------- generic f16 MFMA GEMM (16x16x32) ----------------
// C[m][n] = sum_k A[m][k]*Bt[n][k]. A: MxK lda, Bt: NxK ldb (both f16 row-major).
// EPI 1: f32 partials, C += z*M*N.
// EPI 2: fc epilogue: row r -> out[((r&127)*32 + (r>>7))*NV + n] = acc + bias[n], n<N guard.
// EPI 3: f16 out with bias add.  EPI 4: f16 out plain.
template <int BM, int BN, int EPI>
__global__ __launch_bounds__(256) void gemm_f16(
    const _Float16* __restrict__ A, int lda,
    const _Float16* __restrict__ Bt, int ldb,
    void* __restrict__ Cv, const float* __restrict__ bias,
    int M, int N, int ksteps, int ksplit) {
  constexpr int BK = 64;
  __shared__ __attribute__((aligned(16))) _Float16 sA[BM * BK];
  __shared__ __attribute__((aligned(16))) _Float16 sB[BN * BK];
  const int tid = threadIdx.x;
  const int m0 = blockIdx.x * BM, n0 = blockIdx.y * BN;
  const int z = blockIdx.z;
  A += (size_t)z * ksplit;
  Bt += (size_t)z * ksplit;

  constexpr int WM = BM / 2, WN = BN / 2;
  constexpr int MF = WM / 16, NF = WN / 16;
  const int wid = tid >> 6, lane = tid & 63;
  const int wr = wid >> 1, wc = wid & 1;
  const int lr = lane & 15;
  const int lk = (lane >> 4) * 8;

  f32x4 acc[MF][NF] = {};

  for (int kt = 0; kt < ksteps; ++kt) {
    const int kbase = kt * BK;
#pragma unroll
    for (int i = 0; i < BM / 32; i++) {
      int idx = tid + i * 256;
      int row = idx >> 3, seg = idx & 7;
      gld16(A + (size_t)(m0 + row) * lda + kbase + seg * 8, sA + idx * 8);
    }
#pragma unroll
    for (int i = 0; i < BN / 32; i++) {
      int idx = tid + i * 256;
      int row = idx >> 3, seg = idx & 7;
      int gr = n0 + row;
      if (gr >= N) gr = N - 1;  // only possible for EPI==2 (N=10000)
      gld16(Bt + (size_t)gr * ldb + kbase + seg * 8, sB + idx * 8);
    }
    __syncthreads();
#pragma unroll
    for (int kk = 0; kk < 2; ++kk) {
      f16x8 af[MF], bf[NF];
#pragma unroll
      for (int m = 0; m < MF; m++)
        af[m] = *(const f16x8*)&sA[(wr * WM + m * 16 + lr) * BK + kk * 32 + lk];
#pragma unroll
      for (int n = 0; n < NF; n++)
        bf[n] = *(const f16x8*)&sB[(wc * WN + n * 16 + lr) * BK + kk * 32 + lk];
#pragma unroll
      for (int m = 0; m < MF; m++)
#pragma unroll
        for (int n = 0; n < NF; n++)
          acc[m][n] = __builtin_amdgcn_mfma_f32_16x16x32_f16(af[m], bf[n], acc[m][n], 0, 0, 0);
    }
    __syncthreads();
  }

  const int rowb = (lane >> 4) * 4;
#pragma unroll
  for (int m = 0; m < MF; m++) {
    int gm = m0 + wr * WM + m * 16 + rowb;
#pragma unroll
    for (int n = 0; n < NF; n++) {
      int gn = n0 + wc * WN + n * 16 + lr;
#pragma unroll
      for (int j = 0; j < 4; j++) {
        int r = gm + j;
        if (EPI == 1) {
          float* C = (float*)Cv + (size_t)z * M * N;
          C[(size_t)r * N + gn] = acc[m][n][j];
        } else if (EPI == 2) {
          if (gn < N) {
            int t = r >> 7, b = r & 127;
            ((float*)Cv)[((size_t)(b * NT + t)) * NV + gn] = acc[m][n][j] + bias[gn];
          }
        } else if (EPI == 3) {
          ((_Float16*)Cv)[(size_t)r * N + gn] = (_Float16)(acc[m][n][j] + bias[gn]);
        } else {
          ((_Float16*)Cv)[(size_t)r * N + gn] = (_Float16)acc[m][n][j];
        }
      }
    }
  }
}

// ---------------- g2 GEMM + fused LSTM epilogue ----------------
// C = ctx16 (128x768) @ Wc_int.T (3072x768), interleaved cols j' = 4*hh+gate.
// Epilogue: gates = C + g1p[2][b][768+j'] + Gemb_t[b][j'] + bias_int[j'] -> LSTM.
__global__ __launch_bounds__(256) void k_g2lstm(
    const _Float16* __restrict__ A, const _Float16* __restrict__ Bt,
    const float* __restrict__ g1, const _Float16* __restrict__ ge_t,
    const float* __restrict__ bias_int, float* __restrict__ c, float* __restrict__ h,
    _Float16* __restrict__ h16, _Float16* __restrict__ Hall_t) {
  constexpr int BK = 64;
  __shared__ __attribute__((aligned(16))) _Float16 sA[64 * BK];
  __shared__ __attribute__((aligned(16))) _Float16 sB[64 * BK];
  __shared__ float sC[64 * 68];
  const int tid = threadIdx.x;
  const int m0 = blockIdx.x * 64, n0 = blockIdx.y * 64;

  const int wid = tid >> 6, lane = tid & 63;
  const int wr = wid >> 1, wc = wid & 1;
  const int lr = lane & 15;
  const int lk = (lane >> 4) * 8;

  f32x4 acc[2][2] = {};

  for (int kt = 0; kt < 12; ++kt) {
    const int kbase = kt * BK;
#pragma unroll
    for (int i = 0; i < 2; i++) {
      int idx = tid + i * 256;
      int row = idx >> 3, seg = idx & 7;
      gld16(A + (size_t)(m0 + row) * NH + kbase + seg * 8, sA + idx * 8);
      gld16(Bt + (size_t)(n0 + row) * NH + kbase + seg * 8, sB + idx * 8);
    }
    __syncthreads();
#pragma unroll
    for (int kk = 0; kk < 2; ++kk) {
      f16x8 af[2], bf[2];
#pragma unroll
      for (int m = 0; m < 2; m++)
        af[m] = *(const f16x8*)&sA[(wr * 32 + m * 16 + lr) * BK + kk * 32 + lk];
#pragma unroll
      for (int n = 0; n < 2; n++)
        bf[n] = *(const f16x8*)&sB[(wc * 32 + n * 16 + lr) * BK + kk * 32 + lk];
#pragma unroll
      for (int m = 0; m < 2; m++)
#pragma unroll
        for (int n = 0; n < 2; n++)
          acc[m][n] = __builtin_amdgcn_mfma_f32_16x16x32_f16(af[m], bf[n], acc[m][n], 0, 0, 0);
    }
    __syncthreads();
  }

  // stage tile to LDS (rows = b_local, cols = j'_local, stride 68)
  const int rowb = (lane >> 4) * 4;
#pragma unroll
  for (int m = 0; m < 2; m++) {
    int bl = wr * 32 + m * 16 + rowb;
#pragma unroll
    for (int n = 0; n < 2; n++) {
      int jl = wc * 32 + n * 16 + lr;
#pragma unroll
      for (int j = 0; j < 4; j++) sC[(bl + j) * 68 + jl] = acc[m][n][j];
    }
  }
  __syncthreads();

  // LSTM cells: 64 b x 16 hh per block; thread -> b_local = tid&63, 4 hh's
  const int b_l = tid & 63;
  const int b_g = m0 + b_l;
#pragma unroll
  for (int i = 0; i < 4; i++) {
    int hh_l = (tid >> 6) * 4 + i;
    int hh_g = (n0 >> 2) + hh_l;
    f32x4 g = *(const f32x4*)&sC[b_l * 68 + 4 * hh_l];
    f32x4 p0 = *(const f32x4*)&g1[(size_t)b_g * 3840 + 768 + 4 * hh_g];
    f32x4 p1 = *(const f32x4*)&g1[(size_t)NB * 3840 + (size_t)b_g * 3840 + 768 + 4 * hh_g];
    f16x4 ge = *(const f16x4*)&ge_t[(size_t)b_g * 3072 + 4 * hh_g];
    f32x4 bi = *(const f32x4*)&bias_int[4 * hh_g];
    float gi = g[0] + p0[0] + p1[0] + (float)ge[0] + bi[0];
    float gf = g[1] + p0[1] + p1[1] + (float)ge[1] + bi[1];
    float gg = g[2] + p0[2] + p1[2] + (float)ge[2] + bi[2];
    float go = g[3] + p0[3] + p1[3] + (float)ge[3] + bi[3];
    float cn = sigm(gf) * c[b_g * NH + hh_g] + sigm(gi) * fast_tanh(gg);
    float hn = sigm(go) * fast_tanh(cn);
    c[b_g * NH + hh_g] = cn;
    h[b_g * NH + hh_g] = hn;
    h16[(size_t)b_g * NH + hh_g] = (_Float16)hn;
    Hall_t[(size_t)b_g * NH + hh_g] = (_Float16)hn;
  }
}

// ---------------- fused attention: scores + softmax + ctx ----------------
__global__ __launch_bounds__(256) void k_attn(
    const _Float16* __restrict__ fp, const float* __restrict__ g1,
    const float* __restrict__ v, const _Float16* __restrict__ feat16,
    _Float16* __restrict__ ctx16) {
  __shared__ float hw[NH], vv[NH], sc[NR], al[64];
  const int b = blockIdx.x, tid = threadIdx.x;
  for (int i = tid; i < NH; i += 256) {
    hw[i] = g1[(size_t)b * 3840 + i] + g1[(size_t)NB * 3840 + (size_t)b * 3840 + i];
    vv[i] = v[i];
  }
  __syncthreads();
  const int wid = tid >> 6, lane = tid & 63;
  for (int r = wid; r < NR; r += 4) {
    const _Float16* fpr = fp + (size_t)(b * NR + r) * NH;
    float s = 0.f;
#pragma unroll
    for (int it = 0; it < 3; it++) {
      int hh = it * 256 + lane * 4;
      f16x4 fv = *(const f16x4*)(fpr + hh);
#pragma unroll
      for (int j = 0; j < 4; j++) s += fast_tanh((float)fv[j] + hw[hh + j]) * vv[hh + j];
    }
#pragma unroll
    for (int off = 32; off; off >>= 1) s += __shfl_down(s, off);
    if (lane == 0) sc[r] = s;
  }
  __syncthreads();
  if (tid < 64) {
    float s = (tid < NR) ? sc[tid] : -1e30f;
    float m = s;
#pragma unroll
    for (int off = 32; off; off >>= 1) m = fmaxf(m, __shfl_xor(m, off));
    float e = (tid < NR) ? __expf(s - m) : 0.f;
    float su = e;
#pragma unroll
    for (int off = 32; off; off >>= 1) su += __shfl_xor(su, off);
    al[tid] = e / su;
  }
  __syncthreads();
#pragma unroll
  for (int j = 0; j < 3; j++) {
    int f = tid + j * 256;
    const _Float16* fb = feat16 + (size_t)b * NR * NH + f;
    float acc = 0.f;
#pragma unroll
    for (int r = 0; r < NR; r++) acc += al[r] * (float)fb[(size_t)r * NH];
    ctx16[(size_t)b * NH + f] = (_Float16)acc;
  }
}

// ---------------- prep kernels ----------------
__global__ void k_f32_to_f16(const float* __restrict__ src, _Float16* __restrict__ dst, int n) {
  int i = blockIdx.x * 256 + threadIdx.x;
  if (i < n) dst[i] = (_Float16)src[i];
}

// interleaved gate weights: j' = 4*hh + gate  (src row = gate*768 + hh)
__global__ void k_wint(const float* __restrict__ W_ih, const float* __restrict__ W_hh,
                       _Float16* __restrict__ We_int, _Float16* __restrict__ Wc_int,
                       _Float16* __restrict__ W1) {
  int jp = blockIdx.x;  // 0..3071
  int k = blockIdx.y * 256 + threadIdx.x;
  int src = (jp & 3) * NH + (jp >> 2);
  We_int[(size_t)jp * NH + k] = (_Float16)W_ih[(size_t)src * 1536 + k];
  Wc_int[(size_t)jp * NH + k] = (_Float16)W_ih[(size_t)src * 1536 + 768 + k];
  W1[(size_t)(768 + jp) * NH + k] = (_Float16)W_hh[(size_t)src * NH + k];
}

// Wh rows of W1: W1[j][k] = attn_W[j][768+k]
__global__ void k_wh(const float* __restrict__ attn_W, _Float16* __restrict__ W1) {
  int j = blockIdx.x;
  int k = blockIdx.y * 256 + threadIdx.x;
  W1[(size_t)j * NH + k] = (_Float16)attn_W[(size_t)j * 1536 + 768 + k];
}

__global__ void k_bias(const float* __restrict__ b_ih, const float* __restrict__ b_hh,
                       float* __restrict__ bias_int) {
  int jp = blockIdx.x * 256 + threadIdx.x;  // 3072
  int src = (jp & 3) * NH + (jp >> 2);
  bias_int[jp] = b_ih[src] + b_hh[src];
}

// emb16[t*128+b] = emb_W[captions[b,t]]
__global__ void k_emb2(const int* __restrict__ captions, const float* __restrict__ emb_W,
                       _Float16* __restrict__ emb16) {
  int row = blockIdx.x;
  int k = blockIdx.y * 256 + threadIdx.x;
  int t = row >> 7, b = row & 127;
  int tok = captions[b * NT + t];
  emb16[(size_t)row * NH + k] = (_Float16)emb_W[(size_t)tok * NH + k];
}

__global__ void k_init(const float* __restrict__ features, float* __restrict__ h,
                       float* __restrict__ c, _Float16* __restrict__ h16) {
  int b = blockIdx.x;
  int f = blockIdx.y * 256 + threadIdx.x;
  float s = 0.f;
#pragma unroll 7
  for (int r = 0; r < NR; r++) s += features[((size_t)(b * NR + r)) * NH + f];
  float h0 = tanhf(s * (1.f / 49.f));
  h[b * NH + f] = h0;
  c[b * NH + f] = 0.f;
  h16[(size_t)b * NH + f] = (_Float16)h0;
}

__global__ void k_tail(const float* __restrict__ h, const float* __restrict__ c,
                       float* __restrict__ out) {
  int i = blockIdx.x * 256 + threadIdx.x;  // 98304
  out[OUT_ELEMS + i] = h[i];
  out[OUT_ELEMS + NB * NH + i] = c[i];
}

// ---------------- host ----------------
extern "C" void kernel_launch(void* const* d_in, const int* in_sizes, int n_in,
                              void* d_out, int out_size, void* d_ws, size_t ws_size,
                              hipStream_t stream) {
  const float* features = (const float*)d_in[0];
  const int* captions = (const int*)d_in[1];
  const float* emb_W = (const float*)d_in[2];
  const float* attn_W = (const float*)d_in[3];
  const float* attn_b = (const float*)d_in[4];
  const float* attnv_W = (const float*)d_in[5];
  // d_in[6] attnv_b: constant shift, cancels in softmax
  const float* W_ih = (const float*)d_in[7];
  const float* W_hh = (const float*)d_in[8];
  const float* b_ih = (const float*)d_in[9];
  const float* b_hh = (const float*)d_in[10];
  const float* fc_W = (const float*)d_in[11];
  const float* fc_b = (const float*)d_in[12];
  float* out = (float*)d_out;

  char* p = (char*)d_ws;
  _Float16* Gemb16 = (_Float16*)p;  p += 25165824;  // (4096,3072) interleaved; aliased by fcW16
  _Float16* fcW16 = Gemb16;                         // (10000,768), reuse after loop
  _Float16* emb16 = (_Float16*)p;   p += 6291456;   // (4096,768): row t*128+b
  _Float16* feat16 = (_Float16*)p;  p += 9633792;   // (6272,768)
  _Float16* fp16 = (_Float16*)p;    p += 9633792;   // feat_proj + attn_b (6272,768)
  _Float16* attnW16 = (_Float16*)p; p += 2359296;   // (768,1536)
  _Float16* W1 = (_Float16*)p;      p += 5898240;   // (3840,768): [Wh ; Whh_int]
  _Float16* We_int = (_Float16*)p;  p += 4718592;   // (3072,768)
  _Float16* Wc_int = (_Float16*)p;  p += 4718592;   // (3072,768)
  _Float16* H_all = (_Float16*)p;   p += 6291456;   // (4096,768): row t*128+b
  float* g1 = (float*)p;            p += 3932160;   // 2 x (128,3840)
  float* bias_int = (float*)p;      p += 12288;     // (3072,)
  _Float16* ctx16 = (_Float16*)p;   p += 196608;    // (128,768)
  _Float16* h16 = (_Float16*)p;     p += 196608;    // (128,768)
  float* hbuf = (float*)p;          p += 393216;
  float* cbuf = (float*)p;          p += 393216;    // ~80 MB total

  // ---- phase A ----
  k_f32_to_f16<<<dim3(18816), 256, 0, stream>>>(features, feat16, 4816896);
  k_f32_to_f16<<<dim3(4608), 256, 0, stream>>>(attn_W, attnW16, 1179648);
  k_wint<<<dim3(3072, 3), 256, 0, stream>>>(W_ih, W_hh, We_int, Wc_int, W1);
  k_wh<<<dim3(768, 3), 256, 0, stream>>>(attn_W, W1);
  k_bias<<<dim3(12), 256, 0, stream>>>(b_ih, b_hh, bias_int);
  k_emb2<<<dim3(4096, 3), 256, 0, stream>>>(captions, emb_W, emb16);
  k_init<<<dim3(128, 3), 256, 0, stream>>>(features, hbuf, cbuf, h16);
  // fp16 = features @ Wf.T + attn_b   (6272x768, K=768)
  gemm_f16<128, 128, 3><<<dim3(49, 6, 1), 256, 0, stream>>>(
      feat16, 768, attnW16, 1536, fp16, attn_b, 6272, 768, 12, 0);
  // Gemb = emb @ We_int.T  (4096x3072, K=768), f16, interleaved cols
  gemm_f16<128, 128, 4><<<dim3(32, 24, 1), 256, 0, stream>>>(
      emb16, 768, We_int, 768, Gemb16, nullptr, 4096, 3072, 12, 0);

  // ---- sequential scan: 3 kernels per step ----
  for (int t = 0; t < NT; t++) {
    // g1 = h @ [Wh ; Whh_int].T  (128x3840, K=768, split-K 2, fp32 partials)
    gemm_f16<64, 64, 1><<<dim3(2, 60, 2), 256, 0, stream>>>(
        h16, 768, W1, 768, g1, nullptr, 128, 3840, 6, 384);
    k_attn<<<dim3(128), 256, 0, stream>>>(fp16, g1, attnv_W, feat16, ctx16);
    k_g2lstm<<<dim3(2, 48), 256, 0, stream>>>(
        ctx16, Wc_int, g1, Gemb16 + (size_t)t * NB * 3072, bias_int, cbuf, hbuf, h16,
        H_all + (size_t)t * NB * NH);
  }

  // ---- fc (fcW16 aliases Gemb16, safe after last step in stream order) ----
  k_f32_to_f16<<<dim3(30000), 256, 0, stream>>>(fc_W, fcW16, 7680000);
  gemm_f16<128, 128, 2><<<dim3(32, 79, 1), 256, 0, stream>>>(
      H_all, 768, fcW16, 768, out, fc_b, 4096, 10000, 12, 0);
  k_tail<<<dim3(384), 256, 0, stream>>>(hbuf, cbuf, out);
}